// Round 7
// baseline (190.534 us; speedup 1.0000x reference)
//
#include <hip/hip_runtime.h>
#include <hip/hip_cooperative_groups.h>

namespace cg = cooperative_groups;

#define N_TOK 8192

typedef _Float16 f16x8 __attribute__((ext_vector_type(8)));
typedef _Float16 f16x4 __attribute__((ext_vector_type(4)));
typedef _Float16 f16x2 __attribute__((ext_vector_type(2)));
typedef float    f32x4 __attribute__((ext_vector_type(4)));

__device__ __forceinline__ f32x4 mfma_k32(f16x8 a, f16x8 b, f32x4 c) {
  return __builtin_amdgcn_mfma_f32_16x16x32_f16(a, b, c, 0, 0, 0);
}
__device__ __forceinline__ f32x4 mfma_k16(f16x4 a, f16x4 b, f32x4 c) {
  // legacy spelling: no underscore before f16
  return __builtin_amdgcn_mfma_f32_16x16x16f16(a, b, c, 0, 0, 0);
}

// QSCALE^2 = log2(e)/sqrt(32); fold softmax scale + ln->log2 into q so
// s2[n,m] = qe_n . qe_m is directly the exp2 exponent.
#define QSCALE 0.50500977f

// ---------------------------------------------------------------------------
// ONE cooperative kernel, 256 blocks x 1024 thr (= 1 block/CU, grid resident).
// Phase A: qe = fp16((W x + b)*QSCALE); vp = fragment-packed fp16(x).
//   vp[g][c][quad][nt][j] = x[c][g*32 + nt*16 + quad*4 + j]  (g = n/32)
//   -> a PV A-fragment load is ONE f16x8/lane, 1 KB contiguous per wave.
// Phase B: Bn[n] = log2(sum_m exp2(qe_n . qe_m))   (32 n-rows per block)
// Phase C: out[c,m] = sum_n vp[c,n]*exp2(qe_n.qe_m - Bn[n]) + x
//   block = 32 m-cols, 16 waves split n 16-way (512 each, 16 chunks of 32).
//   In-register S->P->PV: exp2'd S frag in C/D layout IS a K16 B-fragment.
// ---------------------------------------------------------------------------
__global__ __launch_bounds__(1024, 4) void mega_kernel(
    const float* __restrict__ x, const float* __restrict__ W,
    const float* __restrict__ bias, _Float16* __restrict__ qe,
    _Float16* __restrict__ vp, float* __restrict__ Bn,
    float* __restrict__ out) {
  __shared__ float smem[8 * 64 * 33];  // 67584 B; aliased per phase
  cg::grid_group grid = cg::this_grid();
  int t = threadIdx.x, blk = blockIdx.x;
  int w = t >> 6, lane = t & 63, quad = lane >> 4, l15 = lane & 15;

  // ----------------- Phase A: projection + V pack -----------------
  {
    float* Wl = smem;  // [32][65]
    for (int i = t; i < 2048; i += 1024) Wl[(i >> 6) * 65 + (i & 63)] = W[i];
    __syncthreads();
    int g = blk * 1024 + t;  // 262144 threads = 8192 n x 32 o
    int o = g & 31, n = g >> 5;
    float acc0 = bias[o], acc1 = 0.f;
#pragma unroll
    for (int c = 0; c < 32; ++c) {
      acc0 = fmaf(Wl[o * 65 + c], x[c * N_TOK + n], acc0);
      acc1 = fmaf(Wl[o * 65 + 32 + c], x[(32 + c) * N_TOK + n], acc1);
    }
    qe[n * 32 + o] = (_Float16)((acc0 + acc1) * QSCALE);
    // V pack: each thread converts one float2 of x into vp
    int f = g * 2;
    int c = f >> 13, n2 = f & 8191;  // f even -> both elems same row c
    float2 xv = *(const float2*)(x + f);
    int gg = n2 >> 5, off = n2 & 31;
    int nt = off >> 4, q2 = (off >> 2) & 3, j = off & 3;  // j in {0,2}
    f16x2 h;
    h[0] = (_Float16)xv.x;
    h[1] = (_Float16)xv.y;
    *(f16x2*)(vp + ((gg * 64 + c) * 4 + q2) * 8 + nt * 4 + j) = h;
  }
  grid.sync();

  // ----------------- Phase B: logsumexp denominators -----------------
  {
    float(*Lp)[32] = reinterpret_cast<float(*)[32]>(smem);
    int n0 = blk * 32;
    f16x8 af0 = *(const f16x8*)(qe + (n0 + l15) * 32 + quad * 8);
    f16x8 af1 = *(const f16x8*)(qe + (n0 + 16 + l15) * 32 + quad * 8);
    const _Float16* qb = qe + (w * 512 + l15) * 32 + quad * 8;
    f16x8 pb0 = *(const f16x8*)(qb);        // prefetched B tiles
    f16x8 pb1 = *(const f16x8*)(qb + 512);  // +16 rows
    f32x4 a00 = {0.f, 0.f, 0.f, 0.f}, a01 = a00, a10 = a00, a11 = a00;
    for (int mt = 0; mt < 16; ++mt) {
      f16x8 b0 = pb0, b1 = pb1;
      int nx = ((mt + 1) & 15) * 1024;  // wrap: always-valid prefetch
      pb0 = *(const f16x8*)(qb + nx);
      pb1 = *(const f16x8*)(qb + nx + 512);
      f32x4 z = {0.f, 0.f, 0.f, 0.f};
      f32x4 s00 = mfma_k32(af0, b0, z);
      f32x4 s01 = mfma_k32(af0, b1, z);
      f32x4 s10 = mfma_k32(af1, b0, z);
      f32x4 s11 = mfma_k32(af1, b1, z);
#pragma unroll
      for (int r = 0; r < 4; ++r) {
        a00[r] += __builtin_amdgcn_exp2f(s00[r]);
        a01[r] += __builtin_amdgcn_exp2f(s01[r]);
        a10[r] += __builtin_amdgcn_exp2f(s10[r]);
        a11[r] += __builtin_amdgcn_exp2f(s11[r]);
      }
    }
    f32x4 sums0 = a00 + a01;  // rows n0 + quad*4 + r
    f32x4 sums1 = a10 + a11;  // rows n0 + 16 + quad*4 + r
#pragma unroll
    for (int r = 0; r < 4; ++r) {
#pragma unroll
      for (int mask = 1; mask < 16; mask <<= 1) {
        sums0[r] += __shfl_xor(sums0[r], mask, 64);
        sums1[r] += __shfl_xor(sums1[r], mask, 64);
      }
    }
    if (l15 == 0) {
      *(f32x4*)&Lp[w][quad * 4] = sums0;
      *(f32x4*)&Lp[w][16 + quad * 4] = sums1;
    }
    __syncthreads();
    if (t < 32) {
      float L = 0.f;
#pragma unroll
      for (int ww = 0; ww < 16; ++ww) L += Lp[ww][t];
      Bn[n0 + t] = __builtin_amdgcn_logf(L);  // v_log_f32 = log2
    }
  }
  grid.sync();

  // ----------------- Phase C: fused softmax-PV -----------------
  {
    float* Ot = smem;  // [8 sets][64 c][33]
    int m0 = blk * 32;
    f16x8 bm0 = *(const f16x8*)(qe + (m0 + l15) * 32 + quad * 8);
    f16x8 bm1 = *(const f16x8*)(qe + (m0 + 16 + l15) * 32 + quad * 8);

    int base = w * 512;  // this wave's n-slice
    const _Float16* qa = qe + (base + l15) * 32 + quad * 8;
    const float* bnb = Bn + base + quad * 4;

    f32x4 acc[4][2];
#pragma unroll
    for (int ct = 0; ct < 4; ++ct)
#pragma unroll
      for (int mt = 0; mt < 2; ++mt) acc[ct][mt] = f32x4{0.f, 0.f, 0.f, 0.f};

    f16x8 an[2][2];  // ping-pong S A-frags
    an[0][0] = *(const f16x8*)(qa);
    an[0][1] = *(const f16x8*)(qa + 512);

#pragma unroll 2
    for (int ch = 0; ch < 16; ++ch) {
      int cur = ch & 1, nxt = cur ^ 1;
      int nb = base + ch * 32;
      // early single-buffered loads (consumed late in the chunk)
      f32x4 Bq0 = *(const f32x4*)(bnb + ch * 32);
      f32x4 Bq1 = *(const f32x4*)(bnb + ch * 32 + 16);
      f16x8 av8[4];
#pragma unroll
      for (int ct = 0; ct < 4; ++ct)
        av8[ct] = *(const f16x8*)(vp + (((nb >> 5) * 64 + ct * 16 + l15) * 4 +
                                        quad) * 8);
      int rnx = ((ch + 1) & 15) * 32;  // wrap: always-valid prefetch
      an[nxt][0] = *(const f16x8*)(qa + rnx * 32);
      an[nxt][1] = *(const f16x8*)(qa + rnx * 32 + 512);

      f32x4 z = {0.f, 0.f, 0.f, 0.f};
      f32x4 s00 = mfma_k32(an[cur][0], bm0, z);
      f32x4 s01 = mfma_k32(an[cur][0], bm1, z);
      f32x4 s10 = mfma_k32(an[cur][1], bm0, z);
      f32x4 s11 = mfma_k32(an[cur][1], bm1, z);
      f16x4 p00, p01, p10, p11;
#pragma unroll
      for (int r = 0; r < 4; ++r) {
        p00[r] = (_Float16)__builtin_amdgcn_exp2f(s00[r] - Bq0[r]);
        p01[r] = (_Float16)__builtin_amdgcn_exp2f(s01[r] - Bq0[r]);
        p10[r] = (_Float16)__builtin_amdgcn_exp2f(s10[r] - Bq1[r]);
        p11[r] = (_Float16)__builtin_amdgcn_exp2f(s11[r] - Bq1[r]);
      }
#pragma unroll
      for (int ct = 0; ct < 4; ++ct) {
        f16x4 lo = __builtin_shufflevector(av8[ct], av8[ct], 0, 1, 2, 3);
        f16x4 hi = __builtin_shufflevector(av8[ct], av8[ct], 4, 5, 6, 7);
        acc[ct][0] = mfma_k16(lo, p00, acc[ct][0]);
        acc[ct][1] = mfma_k16(lo, p01, acc[ct][1]);
        acc[ct][0] = mfma_k16(hi, p10, acc[ct][0]);
        acc[ct][1] = mfma_k16(hi, p11, acc[ct][1]);
      }
    }

    // Combine across 16 waves (16 -> 8 -> 1), then store out = sum + x.
    if (w < 8) {
#pragma unroll
      for (int ct = 0; ct < 4; ++ct)
#pragma unroll
        for (int mt = 0; mt < 2; ++mt)
#pragma unroll
          for (int r = 0; r < 4; ++r)
            Ot[(w * 64 + ct * 16 + quad * 4 + r) * 33 + mt * 16 + l15] =
                acc[ct][mt][r];
    }
    __syncthreads();
    if (w >= 8) {
#pragma unroll
      for (int ct = 0; ct < 4; ++ct)
#pragma unroll
        for (int mt = 0; mt < 2; ++mt)
#pragma unroll
          for (int r = 0; r < 4; ++r)
            Ot[((w - 8) * 64 + ct * 16 + quad * 4 + r) * 33 + mt * 16 + l15] +=
                acc[ct][mt][r];
    }
    __syncthreads();
    // 2048 outputs, 1024 threads -> 2 each
    for (int idx = t; idx < 2048; idx += 1024) {
      int cc = idx >> 5, m = idx & 31;
      float v = 0.f;
#pragma unroll
      for (int s = 0; s < 8; ++s) v += Ot[(s * 64 + cc) * 33 + m];
      out[cc * N_TOK + m0 + m] = v + x[cc * N_TOK + m0 + m];
    }
  }
}

// ---------------------------------------------------------------------------
extern "C" void kernel_launch(void* const* d_in, const int* in_sizes, int n_in,
                              void* d_out, int out_size, void* d_ws,
                              size_t ws_size, hipStream_t stream) {
  const float* x = (const float*)d_in[0];     // [64][8192]
  const float* W = (const float*)d_in[1];     // [32][64]
  const float* bias = (const float*)d_in[2];  // [32]
  float* out = (float*)d_out;                 // [64][8192]

  char* ws = (char*)d_ws;
  _Float16* qe = (_Float16*)ws;                 // 8192*32*2 = 512 KB
  _Float16* vp = (_Float16*)(ws + 524288);      // 64*8192*2 = 1 MB (packed V)
  float* Bn = (float*)(ws + 524288 + 1048576);  // 8192*4 = 32 KB

  void* args[] = {(void*)&x,  (void*)&W,  (void*)&bias, (void*)&qe,
                  (void*)&vp, (void*)&Bn, (void*)&out};
  hipLaunchCooperativeKernel((void*)mega_kernel, dim3(256), dim3(1024), args,
                             0, stream);
}